// Round 1
// baseline (818.563 us; speedup 1.0000x reference)
//
#include <hip/hip_runtime.h>
#include <math.h>

typedef short bf16x8 __attribute__((ext_vector_type(8)));
typedef float f32x4 __attribute__((ext_vector_type(4)));

__device__ __forceinline__ short f2bf(float f) {
    union { float f; unsigned u; } v; v.f = f;
    unsigned r = v.u + 0x7fffu + ((v.u >> 16) & 1u);
    return (short)(r >> 16);
}

// shifted softplus: 2*log(1+exp(0.5x)), linear passthrough handled by the
// numerically-stable form (difference < 2e-6 vs reference's hard switch)
__device__ __forceinline__ float ssp(float x) {
    float h = 0.5f * x;
    return 2.0f * (fmaxf(h, 0.0f) + __logf(1.0f + __expf(-fabsf(h))));
}

__global__ __launch_bounds__(256, 2) void cfconv_kernel(
    const float* __restrict__ nw, const float* __restrict__ rbf,
    const float* __restrict__ W1, const float* __restrict__ b1,
    const float* __restrict__ W2, const float* __restrict__ b2,
    const int* __restrict__ src, const int* __restrict__ dst,
    float* __restrict__ out, int n_edges)
{
    // per-wave H tile for C-layout -> A-layout transform; stride 72 keeps
    // ds_read_b128 16B-aligned (144B rows) and limits conflicts to 2-way (free)
    __shared__ __align__(16) short lds_h[4][16 * 72];

    const int tid  = threadIdx.x;
    const int wave = tid >> 6;
    const int lane = tid & 63;
    const int l16  = lane & 15;
    const int quad = lane >> 4;

    // W1/W2 in B-operand fragment layout, held in registers for the whole kernel.
    // B[k][n]: n = l16 + 16*nt, k = quad*8 + j + 32*ks   (W stored [in][out])
    bf16x8 w1f[2][4], w2f[2][4];
    #pragma unroll
    for (int ks = 0; ks < 2; ++ks) {
        #pragma unroll
        for (int nt = 0; nt < 4; ++nt) {
            const int col = l16 + 16 * nt;
            const int k0  = quad * 8 + 32 * ks;
            bf16x8 a, b;
            #pragma unroll
            for (int j = 0; j < 8; ++j) {
                a[j] = f2bf(W1[(k0 + j) * 64 + col]);
                b[j] = f2bf(W2[(k0 + j) * 64 + col]);
            }
            w1f[ks][nt] = a;
            w2f[ks][nt] = b;
        }
    }
    float b1v[4], b2v[4];
    #pragma unroll
    for (int nt = 0; nt < 4; ++nt) {
        b1v[nt] = b1[l16 + 16 * nt];
        b2v[nt] = b2[l16 + 16 * nt];
    }

    short* myh = lds_h[wave];
    const int ntiles = (n_edges + 15) >> 4;
    const int gw = blockIdx.x * 4 + wave;
    const int stride = gridDim.x * 4;

    for (int t = gw; t < ntiles; t += stride) {
        const int e0 = t * 16;

        // A fragments for GEMM1: A[m][k] with m=l16 (edge row), k=quad*8+j+32ks
        int arow = e0 + l16;
        if (arow >= n_edges) arow = n_edges - 1;   // safe clamp (E%16==0 normally)
        const float* rp = rbf + (size_t)arow * 64 + quad * 8;
        bf16x8 af[2];
        #pragma unroll
        for (int ks = 0; ks < 2; ++ks) {
            float4 lo = *(const float4*)(rp + 32 * ks);
            float4 hi = *(const float4*)(rp + 32 * ks + 4);
            bf16x8 a;
            a[0] = f2bf(lo.x); a[1] = f2bf(lo.y); a[2] = f2bf(lo.z); a[3] = f2bf(lo.w);
            a[4] = f2bf(hi.x); a[5] = f2bf(hi.y); a[6] = f2bf(hi.z); a[7] = f2bf(hi.w);
            af[ks] = a;
        }

        // GEMM1: H = rbf @ W1
        f32x4 acc[4] = { {0.f,0.f,0.f,0.f}, {0.f,0.f,0.f,0.f},
                         {0.f,0.f,0.f,0.f}, {0.f,0.f,0.f,0.f} };
        #pragma unroll
        for (int nt = 0; nt < 4; ++nt)
            #pragma unroll
            for (int ks = 0; ks < 2; ++ks)
                acc[nt] = __builtin_amdgcn_mfma_f32_16x16x32_bf16(
                    af[ks], w1f[ks][nt], acc[nt], 0, 0, 0);

        // bias + shifted softplus, write to LDS transposing C-layout -> A-layout
        // C/D: col = l16 + 16*nt (hidden dim), row = quad*4 + r (edge row)
        #pragma unroll
        for (int nt = 0; nt < 4; ++nt)
            #pragma unroll
            for (int r = 0; r < 4; ++r)
                myh[(quad * 4 + r) * 72 + l16 + 16 * nt] =
                    f2bf(ssp(acc[nt][r] + b1v[nt]));

        // read back in A layout (same wave; compiler inserts lgkmcnt wait)
        bf16x8 hf[2];
        #pragma unroll
        for (int ks = 0; ks < 2; ++ks)
            hf[ks] = *(const bf16x8*)(myh + l16 * 72 + quad * 8 + 32 * ks);

        // GEMM2: E2 = H @ W2
        f32x4 acc2[4] = { {0.f,0.f,0.f,0.f}, {0.f,0.f,0.f,0.f},
                          {0.f,0.f,0.f,0.f}, {0.f,0.f,0.f,0.f} };
        #pragma unroll
        for (int nt = 0; nt < 4; ++nt)
            #pragma unroll
            for (int ks = 0; ks < 2; ++ks)
                acc2[nt] = __builtin_amdgcn_mfma_f32_16x16x32_bf16(
                    hf[ks], w2f[ks][nt], acc2[nt], 0, 0, 0);

        // epilogue: m = nw[src] * e2, scatter-add to out[dst]
        #pragma unroll
        for (int r = 0; r < 4; ++r) {
            const int e = e0 + quad * 4 + r;
            if (e < n_edges) {
                const int s = src[e], d = dst[e];
                const float* nwp = nw + (size_t)s * 64;
                float* op = out + (size_t)d * 64;
                #pragma unroll
                for (int nt = 0; nt < 4; ++nt) {
                    const int col = l16 + 16 * nt;
                    atomicAdd(op + col, (acc2[nt][r] + b2v[nt]) * nwp[col]);
                }
            }
        }
    }
}

extern "C" void kernel_launch(void* const* d_in, const int* in_sizes, int n_in,
                              void* d_out, int out_size, void* d_ws, size_t ws_size,
                              hipStream_t stream) {
    const float* nw  = (const float*)d_in[0];
    const float* rbf = (const float*)d_in[1];
    const float* W1  = (const float*)d_in[2];
    const float* b1  = (const float*)d_in[3];
    const float* W2  = (const float*)d_in[4];
    const float* b2  = (const float*)d_in[5];
    const int*   src = (const int*)d_in[6];
    const int*   dst = (const int*)d_in[7];
    float* out = (float*)d_out;
    const int n_edges = in_sizes[6];

    hipMemsetAsync(out, 0, (size_t)out_size * sizeof(float), stream);

    const int blocks = 1024;   // 4 blocks/CU target; grid-stride over edge tiles
    hipLaunchKernelGGL(cfconv_kernel, dim3(blocks), dim3(256), 0, stream,
                       nw, rbf, W1, b1, W2, b2, src, dst, out, n_edges);
}